// Round 1
// 315.651 us; speedup vs baseline: 1.0459x; 1.0459x over previous
//
#include <hip/hip_runtime.h>
#include <hip/hip_bf16.h>

#define NNODES 50000
#define NPAD   50048                 // 3128 row-tiles of 16 (covers 391*128)
#define NEDGES 800000
#define CAP 64                       // padded-CSR capacity (max degree ~45, Poisson(16))
#define RSQRT_D 0.17677669529663687f // 1/sqrt(32)

typedef short short8 __attribute__((ext_vector_type(8)));   // 8 bf16 (4 VGPRs)
typedef float f32x4 __attribute__((ext_vector_type(4)));    // MFMA accumulator

__device__ inline unsigned short f2bf(float f) {
    union { float f; unsigned u; } v; v.f = f;
    unsigned r = (v.u + 0x7fff + ((v.u >> 16) & 1)) >> 16;   // round-to-nearest-even
    return (unsigned short)r;
}
__device__ inline float bf2f(unsigned short u) {
    union { unsigned u; float f; } v; v.u = ((unsigned)u) << 16;
    return v.f;
}
// packed-bf16 dword -> two floats: 1 VALU op each (lshl / and), no extract needed
__device__ inline float bflo(unsigned u) {
    union { unsigned u; float f; } v; v.u = u << 16; return v.f;
}
__device__ inline float bfhi(unsigned u) {
    union { unsigned u; float f; } v; v.u = u & 0xffff0000u; return v.f;
}

// ---------------------------------------------------------------------------
// prep_w: Wtf in MFMA-frag-major layout: chunk (ct*32 + kt*4 + quad) holds
// 16 cols x 8 k-values contiguously -> a wave's A-frag load = 1024 B coalesced.
// col 0..415 = Q|K|V|skip. biascat[col] fp32.
// ---------------------------------------------------------------------------
__global__ __launch_bounds__(256) void prep_w(
    const float* __restrict__ Wq, const float* __restrict__ bq,
    const float* __restrict__ Wk, const float* __restrict__ bk,
    const float* __restrict__ Wv, const float* __restrict__ bv,
    const float* __restrict__ Wskip, const float* __restrict__ bskip,
    unsigned short* __restrict__ Wtf, float* __restrict__ biascat)
{
    const int col = blockIdx.x;
    const int k = threadIdx.x;
    float v; float b;
    if (col < 128)      { v = Wq[k * 128 + col];          b = bq[col]; }
    else if (col < 256) { v = Wk[k * 128 + col - 128];    b = bk[col - 128]; }
    else if (col < 384) { v = Wv[k * 128 + col - 256];    b = bv[col - 256]; }
    else                { v = Wskip[k * 32 + col - 384];  b = bskip[col - 384]; }
    const int ct = col >> 4, c16 = col & 15;
    const int kt = k >> 5, quad = (k >> 3) & 3, j = k & 7;
    Wtf[(size_t)(ct * 32 + kt * 4 + quad) * 128 + c16 * 8 + j] = f2bf(v);
    if (k == 0) biascat[col] = b;
}

// ---------------------------------------------------------------------------
// pack_a: y0 = [x, x*t] -> bf16 in frag-major layout y0f (same chunk scheme,
// rows padded/zeroed to NPAD). Coalesced x reads; 16B scattered writes are
// absorbed by L2 (every byte written -> full-line writeback).
// ---------------------------------------------------------------------------
__global__ __launch_bounds__(256) void pack_a(
    const float* __restrict__ x, const float* __restrict__ t,
    unsigned short* __restrict__ y0f)
{
    const int gid = blockIdx.x * 256 + threadIdx.x;   // NPAD*32 threads exactly
    const int row = gid >> 5;
    const int oct = gid & 31;                          // kt*4+quad
    short8 out = {0, 0, 0, 0, 0, 0, 0, 0};
    if (row < NNODES) {
        const int kb = oct * 8;
        const int kx = (kb < 128) ? kb : (kb - 128);
        const float* xr = x + (size_t)row * 128 + kx;
        float4 f0 = *(const float4*)xr;
        float4 f1 = *(const float4*)(xr + 4);
        if (kb >= 128) {
            const float tv = t[row];
            f0.x *= tv; f0.y *= tv; f0.z *= tv; f0.w *= tv;
            f1.x *= tv; f1.y *= tv; f1.z *= tv; f1.w *= tv;
        }
        out[0] = (short)f2bf(f0.x); out[1] = (short)f2bf(f0.y);
        out[2] = (short)f2bf(f0.z); out[3] = (short)f2bf(f0.w);
        out[4] = (short)f2bf(f1.x); out[5] = (short)f2bf(f1.y);
        out[6] = (short)f2bf(f1.z); out[7] = (short)f2bf(f1.w);
    }
    *(short8*)(y0f + (size_t)((row >> 4) * 32 + oct) * 128 + (row & 15) * 8) = out;
}

// ---------------------------------------------------------------------------
// gemm_mfma: OPERAND-SWAPPED, zero-LDS, zero-barrier, all-coalesced.
// A-op = Wtf frags (lane16=col), B-op = y0f frags (lane16=node); D row =
// col-in-tile, D col = node -> each lane stores 4 consecutive cols of one node
// (one packed 8B store per tile). Wave = 32 rows x 6-7 col-tiles; ping-pong
// Wt frags; grid 391 x 4 (col-tiles 7/7/6/6).
// ---------------------------------------------------------------------------
#define LOADW(buf, ct) do {                                                    \
    _Pragma("unroll")                                                          \
    for (int kt_ = 0; kt_ < 8; ++kt_)                                          \
        buf[kt_] = *(const short8*)(Wtf + (size_t)((ct) * 32 + kt_ * 4 + quad) * 128 + l16 * 8); \
} while (0)

#define DOTILE(buf, ct) do {                                                   \
    f32x4 acc0 = {0.f, 0.f, 0.f, 0.f}, acc1 = {0.f, 0.f, 0.f, 0.f};            \
    _Pragma("unroll")                                                          \
    for (int kt_ = 0; kt_ < 8; ++kt_) {                                        \
        acc0 = __builtin_amdgcn_mfma_f32_16x16x32_bf16(buf[kt_], b0[kt_], acc0, 0, 0, 0); \
        acc1 = __builtin_amdgcn_mfma_f32_16x16x32_bf16(buf[kt_], b1[kt_], acc1, 0, 0, 0); \
    }                                                                          \
    const int cb_ = (ct) * 16 + quad * 4;                                      \
    const float4 bias_ = *(const float4*)(biascat + cb_);                      \
    _Pragma("unroll")                                                          \
    for (int s_ = 0; s_ < 2; ++s_) {                                           \
        const int m_ = n0 + s_ * 16 + l16;                                     \
        if (m_ < NNODES) {                                                     \
            const f32x4 a_ = s_ ? acc1 : acc0;                                 \
            const float v0_ = a_[0] + bias_.x, v1_ = a_[1] + bias_.y;          \
            const float v2_ = a_[2] + bias_.z, v3_ = a_[3] + bias_.w;          \
            if ((ct) < 24) {                                                   \
                uint2 pk_;                                                     \
                pk_.x = (unsigned)f2bf(v0_) | ((unsigned)f2bf(v1_) << 16);     \
                pk_.y = (unsigned)f2bf(v2_) | ((unsigned)f2bf(v3_) << 16);     \
                if ((ct) < 8)                                                  \
                    *(uint2*)(Qb + (size_t)m_ * 128 + cb_) = pk_;              \
                else                                                           \
                    *(uint2*)(KVb + (size_t)m_ * 256 + (cb_ - 128)) = pk_;     \
            } else {                                                           \
                *(float4*)(S + (size_t)m_ * 32 + (cb_ - 384)) =                \
                    make_float4(v0_, v1_, v2_, v3_);                           \
            }                                                                  \
        }                                                                      \
    }                                                                          \
} while (0)

__global__ __launch_bounds__(256) void gemm_mfma(
    const unsigned short* __restrict__ y0f,
    const unsigned short* __restrict__ Wtf,
    const float* __restrict__ biascat,
    unsigned short* __restrict__ Qb, unsigned short* __restrict__ KVb,
    float* __restrict__ S)
{
    const int tid = threadIdx.x;
    const int wave = tid >> 6;
    const int lane = tid & 63;
    const int l16 = lane & 15;
    const int quad = lane >> 4;

    const int n0 = blockIdx.x * 128 + wave * 32;   // 32 rows per wave
    const int mt0 = n0 >> 4;
    const int by = blockIdx.y;                     // 0..3
    const int ct0 = by * 7 - ((by >= 2) ? (by - 2) : 0);   // 0,7,14,20
    const int nct = (by < 2) ? 7 : 6;
    const int ctEnd = ct0 + nct;

    // y0 B-frags for both 16-row sets: 1024B coalesced per load
    short8 b0[8], b1[8];
    #pragma unroll
    for (int kt = 0; kt < 8; ++kt) {
        b0[kt] = *(const short8*)(y0f + (size_t)((mt0 + 0) * 32 + kt * 4 + quad) * 128 + l16 * 8);
        b1[kt] = *(const short8*)(y0f + (size_t)((mt0 + 1) * 32 + kt * 4 + quad) * 128 + l16 * 8);
    }

    short8 wa[8], wb[8];                           // ping-pong Wt A-frags
    LOADW(wa, ct0);
    for (int ct = ct0; ct < ctEnd; ct += 2) {
        if (ct + 1 < ctEnd) LOADW(wb, ct + 1);
        DOTILE(wa, ct);
        if (ct + 1 < ctEnd) {
            if (ct + 2 < ctEnd) LOADW(wa, ct + 2);
            DOTILE(wb, ct + 1);
        }
    }
}

// ---------------------------------------------------------------------------
// scatter_fill: padded CSR in ONE pass — no histogram, no prefix scan.
// ---------------------------------------------------------------------------
__global__ __launch_bounds__(256) void scatter_fill(
    const int* __restrict__ ei, const float* __restrict__ ew,
    int* __restrict__ cnt, int2* __restrict__ einfo)
{
    const int e = blockIdx.x * 256 + threadIdx.x;
    if (e >= NEDGES) return;
    const int src = ei[e];
    const int dst = ei[NEDGES + e];
    const int pos = atomicAdd(&cnt[dst], 1);
    if (pos < CAP) {
        int2 v; v.x = src; v.y = __float_as_int(ew[e]);
        einfo[(size_t)dst * CAP + pos] = v;
    }
}

// ---------------------------------------------------------------------------
// agg_pass (v2): one wave per node; 16 lanes per edge (4 edges per batch),
// 16B (8 bf16 dims) per lane. Per 4-edge batch: 1 K-gather + 1 V-gather
// instruction (V via offset:+256B on the same address), dot-reduce = 2
// shuffles (xor 1,2 over the 4-lane head group). The CSR row (CAP=64 = wave
// size) is preloaded into registers once; per-batch edge ids come from
// ds_bpermute, not L2 loads. Gathers are software-pipelined one batch ahead
// so each load gets a full compute-iteration of latency hiding.
// Rank-1 edge-attr decomposition as before: p*(v+e) = p*v + (p*w)*We + p*be.
// ---------------------------------------------------------------------------
__global__ __launch_bounds__(256) void agg_pass(
    const int* __restrict__ cnt, const int2* __restrict__ einfo,
    const float* __restrict__ We, const float* __restrict__ be,
    const unsigned short* __restrict__ Qb, const unsigned short* __restrict__ KVb,
    float* __restrict__ G)
{
    const int tid = threadIdx.x;
    const int node = blockIdx.x * 4 + (tid >> 6);
    if (node >= NNODES) return;
    const int l = tid & 63;
    const int slot = l >> 4;      // which edge of the 4-batch
    const int q = l & 15;         // 16 lanes/edge; lane covers dims q*8..q*8+7
                                  // head = q>>2 (32 dims per head)

    // Q fragment: 8 bf16 -> 8 f32 (1 VALU op per value from packed dwords)
    const uint4 qu = *(const uint4*)(Qb + (size_t)node * 128 + q * 8);
    float qv[8];
    qv[0] = bflo(qu.x); qv[1] = bfhi(qu.x);
    qv[2] = bflo(qu.y); qv[3] = bfhi(qu.y);
    qv[4] = bflo(qu.z); qv[5] = bfhi(qu.z);
    qv[6] = bflo(qu.w); qv[7] = bfhi(qu.w);

    // We/be fragments for this lane's 8 dims (tiny, L2-hot)
    const float4 weA = *(const float4*)(We + q * 8);
    const float4 weB = *(const float4*)(We + q * 8 + 4);
    const float4 beA = *(const float4*)(be + q * 8);
    const float4 beB = *(const float4*)(be + q * 8 + 4);

    // per-head q.We / q.be scalars: partial over 8 dims, reduce over the
    // 4-lane head group (xor 1,2)
    float pw = qv[0]*weA.x + qv[1]*weA.y + qv[2]*weA.z + qv[3]*weA.w
             + qv[4]*weB.x + qv[5]*weB.y + qv[6]*weB.z + qv[7]*weB.w;
    float pb = qv[0]*beA.x + qv[1]*beA.y + qv[2]*beA.z + qv[3]*beA.w
             + qv[4]*beB.x + qv[5]*beB.y + qv[6]*beB.z + qv[7]*beB.w;
    pw += __shfl_xor(pw, 1); pb += __shfl_xor(pb, 1);
    pw += __shfl_xor(pw, 2); pb += __shfl_xor(pb, 2);
    const float qWeS = pw * RSQRT_D;
    const float qbeS = pb * RSQRT_D;

    const int deg = min(cnt[node], CAP);
    const int2* ep = einfo + (size_t)node * CAP;

    // whole CSR row in wave registers (only the lines we'll touch); zeros
    // elsewhere so any shuffled-in garbage is a safe node-0 index
    int2 eall = make_int2(0, 0);
    const int loadN = min(CAP, ((deg + 3) & ~3) + 4);
    if (l < loadN) eall = ep[l];

    float a[8] = {0.f, 0.f, 0.f, 0.f, 0.f, 0.f, 0.f, 0.f};
    float sp = 0.f, spw = 0.f;

    const char* kvb = (const char*)KVb;          // KV row = 512B (K:0..255, V:256..511)
    const unsigned qoff = (unsigned)(q * 16);

    // prologue: fetch batch 0
    int ecx = __shfl(eall.x, slot);
    int ecy = __shfl(eall.y, slot);
    bool vc = (slot < deg);
    {
        const unsigned off = (((unsigned)(vc ? ecx : 0)) << 9) + qoff;
        // loads issued below
        uint4 kw = *(const uint4*)(kvb + off);
        uint4 vw = *(const uint4*)(kvb + off + 256);
        float wc = __int_as_float(ecy);

        for (int jj = 0; jj < deg; jj += 4) {
            // --- prefetch next batch (issued before current compute) ---
            const int nidx = (jj + 4 + slot) & 63;
            const int enx = __shfl(eall.x, nidx);
            const int eny = __shfl(eall.y, nidx);
            const bool vn = (jj + 4 + slot < deg);
            const unsigned offn = (((unsigned)(vn ? enx : 0)) << 9) + qoff;
            const uint4 kwn = *(const uint4*)(kvb + offn);
            const uint4 vwn = *(const uint4*)(kvb + offn + 256);
            const float wn = __int_as_float(eny);

            // --- compute current batch ---
            float d = qv[0]*bflo(kw.x) + qv[1]*bfhi(kw.x)
                    + qv[2]*bflo(kw.y) + qv[3]*bfhi(kw.y)
                    + qv[4]*bflo(kw.z) + qv[5]*bfhi(kw.z)
                    + qv[6]*bflo(kw.w) + qv[7]*bfhi(kw.w);
            d += __shfl_xor(d, 1);
            d += __shfl_xor(d, 2);               // full per-head dot on all 4 lanes
            float p = __expf(d * RSQRT_D + wc * qWeS + qbeS);
            p = vc ? p : 0.f;
            sp += p; spw += p * wc;
            a[0] += p * bflo(vw.x); a[1] += p * bfhi(vw.x);
            a[2] += p * bflo(vw.y); a[3] += p * bfhi(vw.y);
            a[4] += p * bflo(vw.z); a[5] += p * bfhi(vw.z);
            a[6] += p * bflo(vw.w); a[7] += p * bfhi(vw.w);

            kw = kwn; vw = vwn; wc = wn; vc = vn;
        }
    }

    // reduce over the 4 edge slots (lane bits 4,5)
    sp  += __shfl_xor(sp, 16);  sp  += __shfl_xor(sp, 32);
    spw += __shfl_xor(spw, 16); spw += __shfl_xor(spw, 32);
    #pragma unroll
    for (int i = 0; i < 8; ++i) {
        a[i] += __shfl_xor(a[i], 16);
        a[i] += __shfl_xor(a[i], 32);
    }

    // per-head normalize + rank-1 edge-attr contribution
    const float inv = 1.f / (sp + 1e-16f);
    a[0] = (a[0] + spw*weA.x + sp*beA.x) * inv;
    a[1] = (a[1] + spw*weA.y + sp*beA.y) * inv;
    a[2] = (a[2] + spw*weA.z + sp*beA.z) * inv;
    a[3] = (a[3] + spw*weA.w + sp*beA.w) * inv;
    a[4] = (a[4] + spw*weB.x + sp*beB.x) * inv;
    a[5] = (a[5] + spw*weB.y + sp*beB.y) * inv;
    a[6] = (a[6] + spw*weB.z + sp*beB.z) * inv;
    a[7] = (a[7] + spw*weB.w + sp*beB.w) * inv;

    // mean over the 4 heads (lane bits 2,3)
    #pragma unroll
    for (int i = 0; i < 8; ++i) {
        a[i] += __shfl_xor(a[i], 4);
        a[i] += __shfl_xor(a[i], 8);
    }

    if (l < 4) {   // slot 0, q = 0..3 -> dims q*8..q*8+7
        *(float4*)(G + (size_t)node * 32 + q * 8) =
            make_float4(a[0]*0.25f, a[1]*0.25f, a[2]*0.25f, a[3]*0.25f);
        *(float4*)(G + (size_t)node * 32 + q * 8 + 4) =
            make_float4(a[4]*0.25f, a[5]*0.25f, a[6]*0.25f, a[7]*0.25f);
    }
}

// ---------------------------------------------------------------------------
// node_pass: y = tanh(G + S); z = tanh(y @ Wmlp + bmlp);
// out = x*z[:,:128] + z[:,128:]
// ---------------------------------------------------------------------------
__global__ __launch_bounds__(256) void node_pass(
    const float* __restrict__ x,
    const float* __restrict__ G, const float* __restrict__ S,
    const float* __restrict__ Wmlp, const float* __restrict__ bmlp,
    float* __restrict__ out)
{
    __shared__ float Wm[32 * 256];
    __shared__ float bm[256];
    __shared__ float yl[64 * 32];

    const int tid = threadIdx.x;
    for (int i = tid; i < 2048; i += 256)
        *(float4*)&Wm[i * 4] = *(const float4*)(Wmlp + i * 4);
    if (tid < 64)
        *(float4*)&bm[tid * 4] = *(const float4*)(bmlp + tid * 4);

    const int n0 = blockIdx.x * 64;

    for (int idx = tid; idx < 64 * 32; idx += 256) {
        const int nl = idx >> 5, d = idx & 31;
        const int n = n0 + nl;
        float yv = 0.f;
        if (n < NNODES)
            yv = tanhf(G[(size_t)n * 32 + d] + S[(size_t)n * 32 + d]);
        yl[idx] = yv;
    }
    __syncthreads();

    for (int idx = tid; idx < 64 * 128; idx += 256) {
        const int nl = idx >> 7, c = idx & 127;
        const int n = n0 + nl;
        if (n >= NNODES) continue;
        float s1 = bm[c], s2 = bm[c + 128];
        const float* yrow = &yl[nl * 32];
        #pragma unroll
        for (int d = 0; d < 32; ++d) {
            const float yv = yrow[d];
            s1 += yv * Wm[d * 256 + c];
            s2 += yv * Wm[d * 256 + c + 128];
        }
        out[(size_t)n * 128 + c] = x[(size_t)n * 128 + c] * tanhf(s1) + tanhf(s2);
    }
}

// ---------------------------------------------------------------------------
extern "C" void kernel_launch(void* const* d_in, const int* in_sizes, int n_in,
                              void* d_out, int out_size, void* d_ws, size_t ws_size,
                              hipStream_t stream) {
    const float* x     = (const float*)d_in[0];
    const float* t     = (const float*)d_in[1];
    const int*   ei    = (const int*)  d_in[2];
    const float* ew    = (const float*)d_in[3];
    const float* Wq    = (const float*)d_in[4];
    const float* bq    = (const float*)d_in[5];
    const float* Wk    = (const float*)d_in[6];
    const float* bk    = (const float*)d_in[7];
    const float* Wv    = (const float*)d_in[8];
    const float* bv    = (const float*)d_in[9];
    const float* We    = (const float*)d_in[10];
    const float* be    = (const float*)d_in[11];
    const float* Wskip = (const float*)d_in[12];
    const float* bskip = (const float*)d_in[13];
    const float* Wmlp  = (const float*)d_in[14];
    const float* bmlp  = (const float*)d_in[15];

    char* p = (char*)d_ws;
    unsigned short* Qb  = (unsigned short*)p; p += (size_t)NNODES * 128 * 2;
    unsigned short* KVb = (unsigned short*)p; p += (size_t)NNODES * 256 * 2;
    float* S       = (float*)p; p += (size_t)NNODES * 32 * 4;
    float* G       = (float*)p; p += (size_t)NNODES * 32 * 4;
    unsigned short* Wtf = (unsigned short*)p; p += 416 * 256 * 2;
    float* biascat = (float*)p; p += 416 * 4;
    unsigned short* y0f = (unsigned short*)p; p += (size_t)NPAD * 256 * 2;
    int2* einfo    = (int2*)p;  p += (size_t)NNODES * CAP * 8;
    int* cnt       = (int*)p;   p += NNODES * 4;

    hipMemsetAsync(cnt, 0, (size_t)NNODES * sizeof(int), stream);

    prep_w<<<416, 256, 0, stream>>>(Wq, bq, Wk, bk, Wv, bv, Wskip, bskip,
                                    Wtf, biascat);

    pack_a<<<(NPAD * 32) / 256, 256, 0, stream>>>(x, t, y0f);

    scatter_fill<<<NEDGES / 256, 256, 0, stream>>>(ei, ew, cnt, einfo);

    dim3 gg(NPAD / 128, 4);
    gemm_mfma<<<gg, 256, 0, stream>>>(y0f, Wtf, biascat, Qb, KVb, S);

    agg_pass<<<(NNODES + 3) / 4, 256, 0, stream>>>(cnt, einfo, We, be, Qb, KVb, G);

    node_pass<<<(NNODES + 63) / 64, 256, 0, stream>>>(x, G, S, Wmlp, bmlp,
                                                      (float*)d_out);
}

// Round 2
// 285.723 us; speedup vs baseline: 1.1555x; 1.1047x over previous
//
#include <hip/hip_runtime.h>
#include <hip/hip_bf16.h>

#define NNODES 50000
#define NPAD   50048                 // 3128 row-tiles of 16 (covers 391*128)
#define NEDGES 800000
#define CAP 64                       // padded-CSR capacity (max degree ~45, Poisson(16))
#define RSQRT_D 0.17677669529663687f // 1/sqrt(32)

typedef short short8 __attribute__((ext_vector_type(8)));   // 8 bf16 (4 VGPRs)
typedef float f32x4 __attribute__((ext_vector_type(4)));    // MFMA accumulator

__device__ inline unsigned short f2bf(float f) {
    union { float f; unsigned u; } v; v.f = f;
    unsigned r = (v.u + 0x7fff + ((v.u >> 16) & 1)) >> 16;   // round-to-nearest-even
    return (unsigned short)r;
}
__device__ inline float bf2f(unsigned short u) {
    union { unsigned u; float f; } v; v.u = ((unsigned)u) << 16;
    return v.f;
}
// packed-bf16 dword -> two floats: 1 VALU op each (lshl / and), no extract needed
__device__ inline float bflo(unsigned u) {
    union { unsigned u; float f; } v; v.u = u << 16; return v.f;
}
__device__ inline float bfhi(unsigned u) {
    union { unsigned u; float f; } v; v.u = u & 0xffff0000u; return v.f;
}
// branch-free tanh: 1 - 2/(e^{2x}+1). v_exp_f32 + v_rcp_f32, ~1e-6 abs err,
// saturates correctly at +/-inf (exp->inf -> 1; exp->0 -> -1). No divergence.
__device__ inline float fast_tanh(float v) {
    const float e = __expf(2.0f * v);
    return 1.0f - 2.0f * __builtin_amdgcn_rcpf(e + 1.0f);
}

// ---------------------------------------------------------------------------
// prep_w: Wtf in MFMA-frag-major layout: chunk (ct*32 + kt*4 + quad) holds
// 16 cols x 8 k-values contiguously -> a wave's A-frag load = 1024 B coalesced.
// col 0..415 = Q|K|V|skip. biascat[col] fp32.
// ---------------------------------------------------------------------------
__global__ __launch_bounds__(256) void prep_w(
    const float* __restrict__ Wq, const float* __restrict__ bq,
    const float* __restrict__ Wk, const float* __restrict__ bk,
    const float* __restrict__ Wv, const float* __restrict__ bv,
    const float* __restrict__ Wskip, const float* __restrict__ bskip,
    unsigned short* __restrict__ Wtf, float* __restrict__ biascat)
{
    const int col = blockIdx.x;
    const int k = threadIdx.x;
    float v; float b;
    if (col < 128)      { v = Wq[k * 128 + col];          b = bq[col]; }
    else if (col < 256) { v = Wk[k * 128 + col - 128];    b = bk[col - 128]; }
    else if (col < 384) { v = Wv[k * 128 + col - 256];    b = bv[col - 256]; }
    else                { v = Wskip[k * 32 + col - 384];  b = bskip[col - 384]; }
    const int ct = col >> 4, c16 = col & 15;
    const int kt = k >> 5, quad = (k >> 3) & 3, j = k & 7;
    Wtf[(size_t)(ct * 32 + kt * 4 + quad) * 128 + c16 * 8 + j] = f2bf(v);
    if (k == 0) biascat[col] = b;
}

// ---------------------------------------------------------------------------
// pack_a: y0 = [x, x*t] -> bf16 in frag-major layout y0f (same chunk scheme,
// rows padded/zeroed to NPAD). Coalesced x reads; 16B scattered writes are
// absorbed by L2 (every byte written -> full-line writeback).
// ---------------------------------------------------------------------------
__global__ __launch_bounds__(256) void pack_a(
    const float* __restrict__ x, const float* __restrict__ t,
    unsigned short* __restrict__ y0f)
{
    const int gid = blockIdx.x * 256 + threadIdx.x;   // NPAD*32 threads exactly
    const int row = gid >> 5;
    const int oct = gid & 31;                          // kt*4+quad
    short8 out = {0, 0, 0, 0, 0, 0, 0, 0};
    if (row < NNODES) {
        const int kb = oct * 8;
        const int kx = (kb < 128) ? kb : (kb - 128);
        const float* xr = x + (size_t)row * 128 + kx;
        float4 f0 = *(const float4*)xr;
        float4 f1 = *(const float4*)(xr + 4);
        if (kb >= 128) {
            const float tv = t[row];
            f0.x *= tv; f0.y *= tv; f0.z *= tv; f0.w *= tv;
            f1.x *= tv; f1.y *= tv; f1.z *= tv; f1.w *= tv;
        }
        out[0] = (short)f2bf(f0.x); out[1] = (short)f2bf(f0.y);
        out[2] = (short)f2bf(f0.z); out[3] = (short)f2bf(f0.w);
        out[4] = (short)f2bf(f1.x); out[5] = (short)f2bf(f1.y);
        out[6] = (short)f2bf(f1.z); out[7] = (short)f2bf(f1.w);
    }
    *(short8*)(y0f + (size_t)((row >> 4) * 32 + oct) * 128 + (row & 15) * 8) = out;
}

// ---------------------------------------------------------------------------
// gemm_mfma: OPERAND-SWAPPED, zero-LDS, zero-barrier, all-coalesced.
// A-op = Wtf frags (lane16=col), B-op = y0f frags (lane16=node); D row =
// col-in-tile, D col = node -> each lane stores 4 consecutive cols of one node
// (one packed 8B store per tile). Wave = 32 rows x 6-7 col-tiles; ping-pong
// Wt frags; grid 391 x 4 (col-tiles 7/7/6/6).
// ---------------------------------------------------------------------------
#define LOADW(buf, ct) do {                                                    \
    _Pragma("unroll")                                                          \
    for (int kt_ = 0; kt_ < 8; ++kt_)                                          \
        buf[kt_] = *(const short8*)(Wtf + (size_t)((ct) * 32 + kt_ * 4 + quad) * 128 + l16 * 8); \
} while (0)

#define DOTILE(buf, ct) do {                                                   \
    f32x4 acc0 = {0.f, 0.f, 0.f, 0.f}, acc1 = {0.f, 0.f, 0.f, 0.f};            \
    _Pragma("unroll")                                                          \
    for (int kt_ = 0; kt_ < 8; ++kt_) {                                        \
        acc0 = __builtin_amdgcn_mfma_f32_16x16x32_bf16(buf[kt_], b0[kt_], acc0, 0, 0, 0); \
        acc1 = __builtin_amdgcn_mfma_f32_16x16x32_bf16(buf[kt_], b1[kt_], acc1, 0, 0, 0); \
    }                                                                          \
    const int cb_ = (ct) * 16 + quad * 4;                                      \
    const float4 bias_ = *(const float4*)(biascat + cb_);                      \
    _Pragma("unroll")                                                          \
    for (int s_ = 0; s_ < 2; ++s_) {                                           \
        const int m_ = n0 + s_ * 16 + l16;                                     \
        if (m_ < NNODES) {                                                     \
            const f32x4 a_ = s_ ? acc1 : acc0;                                 \
            const float v0_ = a_[0] + bias_.x, v1_ = a_[1] + bias_.y;          \
            const float v2_ = a_[2] + bias_.z, v3_ = a_[3] + bias_.w;          \
            if ((ct) < 24) {                                                   \
                uint2 pk_;                                                     \
                pk_.x = (unsigned)f2bf(v0_) | ((unsigned)f2bf(v1_) << 16);     \
                pk_.y = (unsigned)f2bf(v2_) | ((unsigned)f2bf(v3_) << 16);     \
                if ((ct) < 8)                                                  \
                    *(uint2*)(Qb + (size_t)m_ * 128 + cb_) = pk_;              \
                else                                                           \
                    *(uint2*)(KVb + (size_t)m_ * 256 + (cb_ - 128)) = pk_;     \
            } else {                                                           \
                *(float4*)(S + (size_t)m_ * 32 + (cb_ - 384)) =                \
                    make_float4(v0_, v1_, v2_, v3_);                           \
            }                                                                  \
        }                                                                      \
    }                                                                          \
} while (0)

__global__ __launch_bounds__(256) void gemm_mfma(
    const unsigned short* __restrict__ y0f,
    const unsigned short* __restrict__ Wtf,
    const float* __restrict__ biascat,
    unsigned short* __restrict__ Qb, unsigned short* __restrict__ KVb,
    float* __restrict__ S)
{
    const int tid = threadIdx.x;
    const int wave = tid >> 6;
    const int lane = tid & 63;
    const int l16 = lane & 15;
    const int quad = lane >> 4;

    const int n0 = blockIdx.x * 128 + wave * 32;   // 32 rows per wave
    const int mt0 = n0 >> 4;
    const int by = blockIdx.y;                     // 0..3
    const int ct0 = by * 7 - ((by >= 2) ? (by - 2) : 0);   // 0,7,14,20
    const int nct = (by < 2) ? 7 : 6;
    const int ctEnd = ct0 + nct;

    // y0 B-frags for both 16-row sets: 1024B coalesced per load
    short8 b0[8], b1[8];
    #pragma unroll
    for (int kt = 0; kt < 8; ++kt) {
        b0[kt] = *(const short8*)(y0f + (size_t)((mt0 + 0) * 32 + kt * 4 + quad) * 128 + l16 * 8);
        b1[kt] = *(const short8*)(y0f + (size_t)((mt0 + 1) * 32 + kt * 4 + quad) * 128 + l16 * 8);
    }

    short8 wa[8], wb[8];                           // ping-pong Wt A-frags
    LOADW(wa, ct0);
    for (int ct = ct0; ct < ctEnd; ct += 2) {
        if (ct + 1 < ctEnd) LOADW(wb, ct + 1);
        DOTILE(wa, ct);
        if (ct + 1 < ctEnd) {
            if (ct + 2 < ctEnd) LOADW(wa, ct + 2);
            DOTILE(wb, ct + 1);
        }
    }
}

// ---------------------------------------------------------------------------
// scatter_fill: padded CSR in ONE pass — no histogram, no prefix scan.
// ---------------------------------------------------------------------------
__global__ __launch_bounds__(256) void scatter_fill(
    const int* __restrict__ ei, const float* __restrict__ ew,
    int* __restrict__ cnt, int2* __restrict__ einfo)
{
    const int e = blockIdx.x * 256 + threadIdx.x;
    if (e >= NEDGES) return;
    const int src = ei[e];
    const int dst = ei[NEDGES + e];
    const int pos = atomicAdd(&cnt[dst], 1);
    if (pos < CAP) {
        int2 v; v.x = src; v.y = __float_as_int(ew[e]);
        einfo[(size_t)dst * CAP + pos] = v;
    }
}

// ---------------------------------------------------------------------------
// agg_pass (v2): one wave per node; 16 lanes per edge (4 edges per batch),
// 16B (8 bf16 dims) per lane. Per 4-edge batch: 1 K-gather + 1 V-gather
// instruction, dot-reduce = 2 shuffles. CSR row preloaded into registers;
// per-batch edge ids via ds_bpermute; gathers software-pipelined 1 batch
// ahead. Rank-1 edge-attr decomposition: p*(v+e) = p*v + (p*w)*We + p*be.
// ---------------------------------------------------------------------------
__global__ __launch_bounds__(256) void agg_pass(
    const int* __restrict__ cnt, const int2* __restrict__ einfo,
    const float* __restrict__ We, const float* __restrict__ be,
    const unsigned short* __restrict__ Qb, const unsigned short* __restrict__ KVb,
    float* __restrict__ G)
{
    const int tid = threadIdx.x;
    const int node = blockIdx.x * 4 + (tid >> 6);
    if (node >= NNODES) return;
    const int l = tid & 63;
    const int slot = l >> 4;      // which edge of the 4-batch
    const int q = l & 15;         // 16 lanes/edge; lane covers dims q*8..q*8+7
                                  // head = q>>2 (32 dims per head)

    // Q fragment: 8 bf16 -> 8 f32 (1 VALU op per value from packed dwords)
    const uint4 qu = *(const uint4*)(Qb + (size_t)node * 128 + q * 8);
    float qv[8];
    qv[0] = bflo(qu.x); qv[1] = bfhi(qu.x);
    qv[2] = bflo(qu.y); qv[3] = bfhi(qu.y);
    qv[4] = bflo(qu.z); qv[5] = bfhi(qu.z);
    qv[6] = bflo(qu.w); qv[7] = bfhi(qu.w);

    // We/be fragments for this lane's 8 dims (tiny, L2-hot)
    const float4 weA = *(const float4*)(We + q * 8);
    const float4 weB = *(const float4*)(We + q * 8 + 4);
    const float4 beA = *(const float4*)(be + q * 8);
    const float4 beB = *(const float4*)(be + q * 8 + 4);

    // per-head q.We / q.be scalars: partial over 8 dims, reduce over the
    // 4-lane head group (xor 1,2)
    float pw = qv[0]*weA.x + qv[1]*weA.y + qv[2]*weA.z + qv[3]*weA.w
             + qv[4]*weB.x + qv[5]*weB.y + qv[6]*weB.z + qv[7]*weB.w;
    float pb = qv[0]*beA.x + qv[1]*beA.y + qv[2]*beA.z + qv[3]*beA.w
             + qv[4]*beB.x + qv[5]*beB.y + qv[6]*beB.z + qv[7]*beB.w;
    pw += __shfl_xor(pw, 1); pb += __shfl_xor(pb, 1);
    pw += __shfl_xor(pw, 2); pb += __shfl_xor(pb, 2);
    const float qWeS = pw * RSQRT_D;
    const float qbeS = pb * RSQRT_D;

    const int deg = min(cnt[node], CAP);
    const int2* ep = einfo + (size_t)node * CAP;

    // whole CSR row in wave registers (only the lines we'll touch); zeros
    // elsewhere so any shuffled-in garbage is a safe node-0 index
    int2 eall = make_int2(0, 0);
    const int loadN = min(CAP, ((deg + 3) & ~3) + 4);
    if (l < loadN) eall = ep[l];

    float a[8] = {0.f, 0.f, 0.f, 0.f, 0.f, 0.f, 0.f, 0.f};
    float sp = 0.f, spw = 0.f;

    const char* kvb = (const char*)KVb;          // KV row = 512B (K:0..255, V:256..511)
    const unsigned qoff = (unsigned)(q * 16);

    // prologue: fetch batch 0
    int ecx = __shfl(eall.x, slot);
    int ecy = __shfl(eall.y, slot);
    bool vc = (slot < deg);
    {
        const unsigned off = (((unsigned)(vc ? ecx : 0)) << 9) + qoff;
        uint4 kw = *(const uint4*)(kvb + off);
        uint4 vw = *(const uint4*)(kvb + off + 256);
        float wc = __int_as_float(ecy);

        for (int jj = 0; jj < deg; jj += 4) {
            // --- prefetch next batch (issued before current compute) ---
            const int nidx = (jj + 4 + slot) & 63;
            const int enx = __shfl(eall.x, nidx);
            const int eny = __shfl(eall.y, nidx);
            const bool vn = (jj + 4 + slot < deg);
            const unsigned offn = (((unsigned)(vn ? enx : 0)) << 9) + qoff;
            const uint4 kwn = *(const uint4*)(kvb + offn);
            const uint4 vwn = *(const uint4*)(kvb + offn + 256);
            const float wn = __int_as_float(eny);

            // --- compute current batch ---
            float d = qv[0]*bflo(kw.x) + qv[1]*bfhi(kw.x)
                    + qv[2]*bflo(kw.y) + qv[3]*bfhi(kw.y)
                    + qv[4]*bflo(kw.z) + qv[5]*bfhi(kw.z)
                    + qv[6]*bflo(kw.w) + qv[7]*bfhi(kw.w);
            d += __shfl_xor(d, 1);
            d += __shfl_xor(d, 2);               // full per-head dot on all 4 lanes
            float p = __expf(d * RSQRT_D + wc * qWeS + qbeS);
            p = vc ? p : 0.f;
            sp += p; spw += p * wc;
            a[0] += p * bflo(vw.x); a[1] += p * bfhi(vw.x);
            a[2] += p * bflo(vw.y); a[3] += p * bfhi(vw.y);
            a[4] += p * bflo(vw.z); a[5] += p * bfhi(vw.z);
            a[6] += p * bflo(vw.w); a[7] += p * bfhi(vw.w);

            kw = kwn; vw = vwn; wc = wn; vc = vn;
        }
    }

    // reduce over the 4 edge slots (lane bits 4,5)
    sp  += __shfl_xor(sp, 16);  sp  += __shfl_xor(sp, 32);
    spw += __shfl_xor(spw, 16); spw += __shfl_xor(spw, 32);
    #pragma unroll
    for (int i = 0; i < 8; ++i) {
        a[i] += __shfl_xor(a[i], 16);
        a[i] += __shfl_xor(a[i], 32);
    }

    // per-head normalize + rank-1 edge-attr contribution
    const float inv = 1.f / (sp + 1e-16f);
    a[0] = (a[0] + spw*weA.x + sp*beA.x) * inv;
    a[1] = (a[1] + spw*weA.y + sp*beA.y) * inv;
    a[2] = (a[2] + spw*weA.z + sp*beA.z) * inv;
    a[3] = (a[3] + spw*weA.w + sp*beA.w) * inv;
    a[4] = (a[4] + spw*weB.x + sp*beB.x) * inv;
    a[5] = (a[5] + spw*weB.y + sp*beB.y) * inv;
    a[6] = (a[6] + spw*weB.z + sp*beB.z) * inv;
    a[7] = (a[7] + spw*weB.w + sp*beB.w) * inv;

    // mean over the 4 heads (lane bits 2,3)
    #pragma unroll
    for (int i = 0; i < 8; ++i) {
        a[i] += __shfl_xor(a[i], 4);
        a[i] += __shfl_xor(a[i], 8);
    }

    if (l < 4) {   // slot 0, q = 0..3 -> dims q*8..q*8+7
        *(float4*)(G + (size_t)node * 32 + q * 8) =
            make_float4(a[0]*0.25f, a[1]*0.25f, a[2]*0.25f, a[3]*0.25f);
        *(float4*)(G + (size_t)node * 32 + q * 8 + 4) =
            make_float4(a[4]*0.25f, a[5]*0.25f, a[6]*0.25f, a[7]*0.25f);
    }
}

// ---------------------------------------------------------------------------
// node_pass (v2): Wm lives in VGPRs, not LDS. Each thread's column pair
// (c, c+128) with c = tid&127 is invariant across the node loop, so the 64
// weights it ever needs fit in 64 VGPRs, loaded ONCE from global (coalesced,
// L2-hot). LDS keeps only yl (8 KB -> occupancy no longer LDS-capped).
// Inner loop per node: 8 broadcast ds_read_b128 (y row is wave-uniform:
// nl = 2k + (tid>>7)) + 64 reg-reg FMAs + 2 fast_tanh. Replaces the 64
// stride-256 scalar LDS reads per output that made v1 issue-bound.
// ---------------------------------------------------------------------------
__global__ __launch_bounds__(256, 4) void node_pass(
    const float* __restrict__ x,
    const float* __restrict__ G, const float* __restrict__ S,
    const float* __restrict__ Wmlp, const float* __restrict__ bmlp,
    float* __restrict__ out)
{
    __shared__ float yl[64 * 32];

    const int tid = threadIdx.x;
    const int c = tid & 127;            // fixed output column pair (c, c+128)
    const int half = tid >> 7;          // which node of each row pair

    // Wm columns in registers (64 VGPRs): w1[d]=Wmlp[d][c], w2[d]=Wmlp[d][c+128]
    float w1[32], w2[32];
    #pragma unroll
    for (int d = 0; d < 32; ++d) {
        w1[d] = Wmlp[d * 256 + c];
        w2[d] = Wmlp[d * 256 + c + 128];
    }
    const float b1 = bmlp[c];
    const float b2 = bmlp[c + 128];

    const int n0 = blockIdx.x * 64;

    // stage y = tanh(G+S): 512 float4s by 256 threads, vectorized
    for (int i4 = tid; i4 < 512; i4 += 256) {
        const int n = n0 + (i4 >> 3);
        const int d0 = (i4 & 7) * 4;
        float4 yv = make_float4(0.f, 0.f, 0.f, 0.f);
        if (n < NNODES) {
            const float4 gv = *(const float4*)(G + (size_t)n * 32 + d0);
            const float4 sv = *(const float4*)(S + (size_t)n * 32 + d0);
            yv.x = fast_tanh(gv.x + sv.x);
            yv.y = fast_tanh(gv.y + sv.y);
            yv.z = fast_tanh(gv.z + sv.z);
            yv.w = fast_tanh(gv.w + sv.w);
        }
        *(float4*)&yl[i4 * 4] = yv;
    }
    __syncthreads();

    for (int k = 0; k < 32; ++k) {
        const int nl = 2 * k + half;
        const int n = n0 + nl;
        if (n >= NNODES) continue;

        const float4* yr = (const float4*)&yl[nl * 32];  // wave-uniform -> broadcast
        float s1 = b1, s2 = b2;
        #pragma unroll
        for (int d8 = 0; d8 < 8; ++d8) {
            const float4 y4 = yr[d8];
            s1 = fmaf(y4.x, w1[d8 * 4 + 0], s1);
            s2 = fmaf(y4.x, w2[d8 * 4 + 0], s2);
            s1 = fmaf(y4.y, w1[d8 * 4 + 1], s1);
            s2 = fmaf(y4.y, w2[d8 * 4 + 1], s2);
            s1 = fmaf(y4.z, w1[d8 * 4 + 2], s1);
            s2 = fmaf(y4.z, w2[d8 * 4 + 2], s2);
            s1 = fmaf(y4.w, w1[d8 * 4 + 3], s1);
            s2 = fmaf(y4.w, w2[d8 * 4 + 3], s2);
        }
        const float z1 = fast_tanh(s1);
        const float z2 = fast_tanh(s2);
        out[(size_t)n * 128 + c] = fmaf(x[(size_t)n * 128 + c], z1, z2);
    }
}

// ---------------------------------------------------------------------------
extern "C" void kernel_launch(void* const* d_in, const int* in_sizes, int n_in,
                              void* d_out, int out_size, void* d_ws, size_t ws_size,
                              hipStream_t stream) {
    const float* x     = (const float*)d_in[0];
    const float* t     = (const float*)d_in[1];
    const int*   ei    = (const int*)  d_in[2];
    const float* ew    = (const float*)d_in[3];
    const float* Wq    = (const float*)d_in[4];
    const float* bq    = (const float*)d_in[5];
    const float* Wk    = (const float*)d_in[6];
    const float* bk    = (const float*)d_in[7];
    const float* Wv    = (const float*)d_in[8];
    const float* bv    = (const float*)d_in[9];
    const float* We    = (const float*)d_in[10];
    const float* be    = (const float*)d_in[11];
    const float* Wskip = (const float*)d_in[12];
    const float* bskip = (const float*)d_in[13];
    const float* Wmlp  = (const float*)d_in[14];
    const float* bmlp  = (const float*)d_in[15];

    char* p = (char*)d_ws;
    unsigned short* Qb  = (unsigned short*)p; p += (size_t)NNODES * 128 * 2;
    unsigned short* KVb = (unsigned short*)p; p += (size_t)NNODES * 256 * 2;
    float* S       = (float*)p; p += (size_t)NNODES * 32 * 4;
    float* G       = (float*)p; p += (size_t)NNODES * 32 * 4;
    unsigned short* Wtf = (unsigned short*)p; p += 416 * 256 * 2;
    float* biascat = (float*)p; p += 416 * 4;
    unsigned short* y0f = (unsigned short*)p; p += (size_t)NPAD * 256 * 2;
    int2* einfo    = (int2*)p;  p += (size_t)NNODES * CAP * 8;
    int* cnt       = (int*)p;   p += NNODES * 4;

    hipMemsetAsync(cnt, 0, (size_t)NNODES * sizeof(int), stream);

    prep_w<<<416, 256, 0, stream>>>(Wq, bq, Wk, bk, Wv, bv, Wskip, bskip,
                                    Wtf, biascat);

    pack_a<<<(NPAD * 32) / 256, 256, 0, stream>>>(x, t, y0f);

    scatter_fill<<<NEDGES / 256, 256, 0, stream>>>(ei, ew, cnt, einfo);

    dim3 gg(NPAD / 128, 4);
    gemm_mfma<<<gg, 256, 0, stream>>>(y0f, Wtf, biascat, Qb, KVb, S);

    agg_pass<<<(NNODES + 3) / 4, 256, 0, stream>>>(cnt, einfo, We, be, Qb, KVb, G);

    node_pass<<<(NNODES + 63) / 64, 256, 0, stream>>>(x, G, S, Wmlp, bmlp,
                                                      (float*)d_out);
}

// Round 3
// 262.606 us; speedup vs baseline: 1.2572x; 1.0880x over previous
//
#include <hip/hip_runtime.h>
#include <hip/hip_bf16.h>

#define NNODES 50000
#define NPAD   50048                 // 3128 row-tiles of 16 (covers 391*128)
#define NEDGES 800000
#define CAP 64                       // padded-CSR capacity (max degree ~45, Poisson(16))
#define RSQRT_D 0.17677669529663687f // 1/sqrt(32)

#define SCAT_BLOCKS 3125             // NEDGES/256
#define GEMM_BLOCKS 1564             // 391*4

typedef short short8 __attribute__((ext_vector_type(8)));   // 8 bf16 (4 VGPRs)
typedef float f32x4 __attribute__((ext_vector_type(4)));    // MFMA accumulator

__device__ inline unsigned short f2bf(float f) {
    union { float f; unsigned u; } v; v.f = f;
    unsigned r = (v.u + 0x7fff + ((v.u >> 16) & 1)) >> 16;   // round-to-nearest-even
    return (unsigned short)r;
}
__device__ inline float bf2f(unsigned short u) {
    union { unsigned u; float f; } v; v.u = ((unsigned)u) << 16;
    return v.f;
}
// packed-bf16 dword -> two floats: 1 VALU op each (lshl / and), no extract needed
__device__ inline float bflo(unsigned u) {
    union { unsigned u; float f; } v; v.u = u << 16; return v.f;
}
__device__ inline float bfhi(unsigned u) {
    union { unsigned u; float f; } v; v.u = u & 0xffff0000u; return v.f;
}
// branch-free tanh: 1 - 2/(e^{2x}+1). v_exp_f32 + v_rcp_f32, ~1e-6 abs err,
// saturates correctly at +/-inf. No divergence.
__device__ inline float fast_tanh(float v) {
    const float e = __expf(2.0f * v);
    return 1.0f - 2.0f * __builtin_amdgcn_rcpf(e + 1.0f);
}

// ---------------------------------------------------------------------------
// prep_w: Wtf in MFMA-frag-major layout: chunk (ct*32 + kt*4 + quad) holds
// 16 cols x 8 k-values contiguously -> a wave's A-frag load = 1024 B coalesced.
// col 0..415 = Q|K|V|skip. biascat[col] fp32.
// ---------------------------------------------------------------------------
__global__ __launch_bounds__(256) void prep_w(
    const float* __restrict__ Wq, const float* __restrict__ bq,
    const float* __restrict__ Wk, const float* __restrict__ bk,
    const float* __restrict__ Wv, const float* __restrict__ bv,
    const float* __restrict__ Wskip, const float* __restrict__ bskip,
    unsigned short* __restrict__ Wtf, float* __restrict__ biascat)
{
    const int col = blockIdx.x;
    const int k = threadIdx.x;
    float v; float b;
    if (col < 128)      { v = Wq[k * 128 + col];          b = bq[col]; }
    else if (col < 256) { v = Wk[k * 128 + col - 128];    b = bk[col - 128]; }
    else if (col < 384) { v = Wv[k * 128 + col - 256];    b = bv[col - 256]; }
    else                { v = Wskip[k * 32 + col - 384];  b = bskip[col - 384]; }
    const int ct = col >> 4, c16 = col & 15;
    const int kt = k >> 5, quad = (k >> 3) & 3, j = k & 7;
    Wtf[(size_t)(ct * 32 + kt * 4 + quad) * 128 + c16 * 8 + j] = f2bf(v);
    if (k == 0) biascat[col] = b;
}

// ---------------------------------------------------------------------------
// pack_a: y0 = [x, x*t] -> bf16 in frag-major layout y0f (same chunk scheme,
// rows padded/zeroed to NPAD).
// ---------------------------------------------------------------------------
__global__ __launch_bounds__(256) void pack_a(
    const float* __restrict__ x, const float* __restrict__ t,
    unsigned short* __restrict__ y0f)
{
    const int gid = blockIdx.x * 256 + threadIdx.x;   // NPAD*32 threads exactly
    const int row = gid >> 5;
    const int oct = gid & 31;                          // kt*4+quad
    short8 out = {0, 0, 0, 0, 0, 0, 0, 0};
    if (row < NNODES) {
        const int kb = oct * 8;
        const int kx = (kb < 128) ? kb : (kb - 128);
        const float* xr = x + (size_t)row * 128 + kx;
        float4 f0 = *(const float4*)xr;
        float4 f1 = *(const float4*)(xr + 4);
        if (kb >= 128) {
            const float tv = t[row];
            f0.x *= tv; f0.y *= tv; f0.z *= tv; f0.w *= tv;
            f1.x *= tv; f1.y *= tv; f1.z *= tv; f1.w *= tv;
        }
        out[0] = (short)f2bf(f0.x); out[1] = (short)f2bf(f0.y);
        out[2] = (short)f2bf(f0.z); out[3] = (short)f2bf(f0.w);
        out[4] = (short)f2bf(f1.x); out[5] = (short)f2bf(f1.y);
        out[6] = (short)f2bf(f1.z); out[7] = (short)f2bf(f1.w);
    }
    *(short8*)(y0f + (size_t)((row >> 4) * 32 + oct) * 128 + (row & 15) * 8) = out;
}

// ---------------------------------------------------------------------------
// gemm_scatter: FUSED gemm_mfma + scatter_fill. scatter_fill was a pure-
// latency kernel (VALUBusy 0.45%, 58 us of idle CUs waiting on atomic
// round-trips + random 8B stores); gemm is compute/LDS-free MFMA work.
// Fusing them as block-uniform paths (interleaved 2:1 so both dispatch at
// t=0) overlaps scatter's fabric latency under gemm's MFMA/VALU pipes:
// fused time ~ max(gemm, scatter) instead of gemm + scatter.
// gemm part: OPERAND-SWAPPED, zero-LDS, zero-barrier, all-coalesced.
// ---------------------------------------------------------------------------
#define LOADW(buf, ct) do {                                                    \
    _Pragma("unroll")                                                          \
    for (int kt_ = 0; kt_ < 8; ++kt_)                                          \
        buf[kt_] = *(const short8*)(Wtf + (size_t)((ct) * 32 + kt_ * 4 + quad) * 128 + l16 * 8); \
} while (0)

#define DOTILE(buf, ct) do {                                                   \
    f32x4 acc0 = {0.f, 0.f, 0.f, 0.f}, acc1 = {0.f, 0.f, 0.f, 0.f};            \
    _Pragma("unroll")                                                          \
    for (int kt_ = 0; kt_ < 8; ++kt_) {                                        \
        acc0 = __builtin_amdgcn_mfma_f32_16x16x32_bf16(buf[kt_], b0[kt_], acc0, 0, 0, 0); \
        acc1 = __builtin_amdgcn_mfma_f32_16x16x32_bf16(buf[kt_], b1[kt_], acc1, 0, 0, 0); \
    }                                                                          \
    const int cb_ = (ct) * 16 + quad * 4;                                      \
    const float4 bias_ = *(const float4*)(biascat + cb_);                      \
    _Pragma("unroll")                                                          \
    for (int s_ = 0; s_ < 2; ++s_) {                                           \
        const int m_ = n0 + s_ * 16 + l16;                                     \
        if (m_ < NNODES) {                                                     \
            const f32x4 a_ = s_ ? acc1 : acc0;                                 \
            const float v0_ = a_[0] + bias_.x, v1_ = a_[1] + bias_.y;          \
            const float v2_ = a_[2] + bias_.z, v3_ = a_[3] + bias_.w;          \
            if ((ct) < 24) {                                                   \
                uint2 pk_;                                                     \
                pk_.x = (unsigned)f2bf(v0_) | ((unsigned)f2bf(v1_) << 16);     \
                pk_.y = (unsigned)f2bf(v2_) | ((unsigned)f2bf(v3_) << 16);     \
                if ((ct) < 8)                                                  \
                    *(uint2*)(Qb + (size_t)m_ * 128 + cb_) = pk_;              \
                else                                                           \
                    *(uint2*)(KVb + (size_t)m_ * 256 + (cb_ - 128)) = pk_;     \
            } else {                                                           \
                *(float4*)(S + (size_t)m_ * 32 + (cb_ - 384)) =                \
                    make_float4(v0_, v1_, v2_, v3_);                           \
            }                                                                  \
        }                                                                      \
    }                                                                          \
} while (0)

__global__ __launch_bounds__(256) void gemm_scatter(
    const unsigned short* __restrict__ y0f,
    const unsigned short* __restrict__ Wtf,
    const float* __restrict__ biascat,
    unsigned short* __restrict__ Qb, unsigned short* __restrict__ KVb,
    float* __restrict__ S,
    const int* __restrict__ ei, const float* __restrict__ ew,
    int* __restrict__ cnt, int2* __restrict__ einfo)
{
    const int b = blockIdx.x;
    const int group = b / 3;
    const int r = b - group * 3;

    if (r < 2) {
        // ---- scatter path (block-uniform branch) ----
        const int sb = group * 2 + r;
        if (sb >= SCAT_BLOCKS) return;
        const int e = sb * 256 + threadIdx.x;          // always < NEDGES
        const int src = ei[e];
        const int dst = ei[NEDGES + e];
        const int pos = atomicAdd(&cnt[dst], 1);
        if (pos < CAP) {
            int2 v; v.x = src; v.y = __float_as_int(ew[e]);
            einfo[(size_t)dst * CAP + pos] = v;
        }
        return;
    }

    // ---- gemm path ----
    const int g = group;                               // 0..1563
    const int bx = g % 391;
    const int by = g / 391;                            // 0..3

    const int tid = threadIdx.x;
    const int wave = tid >> 6;
    const int lane = tid & 63;
    const int l16 = lane & 15;
    const int quad = lane >> 4;

    const int n0 = bx * 128 + wave * 32;               // 32 rows per wave
    const int mt0 = n0 >> 4;
    const int ct0 = by * 7 - ((by >= 2) ? (by - 2) : 0);   // 0,7,14,20
    const int nct = (by < 2) ? 7 : 6;
    const int ctEnd = ct0 + nct;

    // y0 B-frags for both 16-row sets: 1024B coalesced per load
    short8 b0[8], b1[8];
    #pragma unroll
    for (int kt = 0; kt < 8; ++kt) {
        b0[kt] = *(const short8*)(y0f + (size_t)((mt0 + 0) * 32 + kt * 4 + quad) * 128 + l16 * 8);
        b1[kt] = *(const short8*)(y0f + (size_t)((mt0 + 1) * 32 + kt * 4 + quad) * 128 + l16 * 8);
    }

    short8 wa[8], wb[8];                           // ping-pong Wt A-frags
    LOADW(wa, ct0);
    for (int ct = ct0; ct < ctEnd; ct += 2) {
        if (ct + 1 < ctEnd) LOADW(wb, ct + 1);
        DOTILE(wa, ct);
        if (ct + 1 < ctEnd) {
            if (ct + 2 < ctEnd) LOADW(wa, ct + 2);
            DOTILE(wb, ct + 1);
        }
    }
}

// ---------------------------------------------------------------------------
// agg_pass (v3): one wave per node; 16 lanes per edge (4 edges per batch),
// 16B (8 bf16 dims) per lane. v3: 4-deep software pipeline — four
// statically-named batch buffers (rule #20: no runtime-indexed arrays), all
// issued before the first consume, so each wave keeps 4 gather-batches
// (8 gather instrs) in flight instead of 1. Targets the outstanding-miss
// x latency limit seen as 183 MB L2-fill @ 3.2 TB/s.
// Rank-1 edge-attr decomposition: p*(v+e) = p*v + (p*w)*We + p*be.
// ---------------------------------------------------------------------------
#define AGG_ISSUE(K, V, W, F, base) do {                                       \
    const int idx_ = ((base) + slot) & 63;                                     \
    const int ex_ = __shfl(eall.x, idx_);                                      \
    const int ey_ = __shfl(eall.y, idx_);                                      \
    F = ((base) + slot) < deg;                                                 \
    const unsigned off_ = (((unsigned)(F ? ex_ : 0)) << 9) + qoff;             \
    K = *(const uint4*)(kvb + off_);                                           \
    V = *(const uint4*)(kvb + off_ + 256);                                     \
    W = __int_as_float(ey_);                                                   \
} while (0)

#define AGG_COMPUTE(K, V, W, F) do {                                           \
    float d_ = qv[0]*bflo(K.x) + qv[1]*bfhi(K.x)                               \
             + qv[2]*bflo(K.y) + qv[3]*bfhi(K.y)                               \
             + qv[4]*bflo(K.z) + qv[5]*bfhi(K.z)                               \
             + qv[6]*bflo(K.w) + qv[7]*bfhi(K.w);                              \
    d_ += __shfl_xor(d_, 1);                                                   \
    d_ += __shfl_xor(d_, 2);                                                   \
    float p_ = __expf(d_ * RSQRT_D + W * qWeS + qbeS);                         \
    p_ = F ? p_ : 0.f;                                                         \
    sp += p_; spw += p_ * W;                                                   \
    a[0] += p_ * bflo(V.x); a[1] += p_ * bfhi(V.x);                            \
    a[2] += p_ * bflo(V.y); a[3] += p_ * bfhi(V.y);                            \
    a[4] += p_ * bflo(V.z); a[5] += p_ * bfhi(V.z);                            \
    a[6] += p_ * bflo(V.w); a[7] += p_ * bfhi(V.w);                            \
} while (0)

__global__ __launch_bounds__(256) void agg_pass(
    const int* __restrict__ cnt, const int2* __restrict__ einfo,
    const float* __restrict__ We, const float* __restrict__ be,
    const unsigned short* __restrict__ Qb, const unsigned short* __restrict__ KVb,
    float* __restrict__ G)
{
    const int tid = threadIdx.x;
    const int node = blockIdx.x * 4 + (tid >> 6);
    if (node >= NNODES) return;
    const int l = tid & 63;
    const int slot = l >> 4;      // which edge of the 4-batch
    const int q = l & 15;         // 16 lanes/edge; lane covers dims q*8..q*8+7
                                  // head = q>>2 (32 dims per head)

    // Q fragment: 8 bf16 -> 8 f32
    const uint4 qu = *(const uint4*)(Qb + (size_t)node * 128 + q * 8);
    float qv[8];
    qv[0] = bflo(qu.x); qv[1] = bfhi(qu.x);
    qv[2] = bflo(qu.y); qv[3] = bfhi(qu.y);
    qv[4] = bflo(qu.z); qv[5] = bfhi(qu.z);
    qv[6] = bflo(qu.w); qv[7] = bfhi(qu.w);

    // We/be fragments for this lane's 8 dims (tiny, L2-hot)
    const float4 weA = *(const float4*)(We + q * 8);
    const float4 weB = *(const float4*)(We + q * 8 + 4);
    const float4 beA = *(const float4*)(be + q * 8);
    const float4 beB = *(const float4*)(be + q * 8 + 4);

    // per-head q.We / q.be scalars: partial over 8 dims, reduce over the
    // 4-lane head group (xor 1,2)
    float pw = qv[0]*weA.x + qv[1]*weA.y + qv[2]*weA.z + qv[3]*weA.w
             + qv[4]*weB.x + qv[5]*weB.y + qv[6]*weB.z + qv[7]*weB.w;
    float pb = qv[0]*beA.x + qv[1]*beA.y + qv[2]*beA.z + qv[3]*beA.w
             + qv[4]*beB.x + qv[5]*beB.y + qv[6]*beB.z + qv[7]*beB.w;
    pw += __shfl_xor(pw, 1); pb += __shfl_xor(pb, 1);
    pw += __shfl_xor(pw, 2); pb += __shfl_xor(pb, 2);
    const float qWeS = pw * RSQRT_D;
    const float qbeS = pb * RSQRT_D;

    const int deg = min(cnt[node], CAP);
    const int2* ep = einfo + (size_t)node * CAP;

    // whole CSR row in wave registers; zeros elsewhere so shuffled-in
    // garbage is a safe node-0 index
    int2 eall = make_int2(0, 0);
    const int loadN = min(CAP, ((deg + 3) & ~3) + 4);
    if (l < loadN) eall = ep[l];

    float a[8] = {0.f, 0.f, 0.f, 0.f, 0.f, 0.f, 0.f, 0.f};
    float sp = 0.f, spw = 0.f;

    const char* kvb = (const char*)KVb;          // KV row = 512B (K:0..255, V:256..511)
    const unsigned qoff = (unsigned)(q * 16);

    // 4-deep pipeline: all four batch buffers issued before first consume.
    uint4 k0, v0, k1, v1, k2, v2, k3, v3;
    float w0, w1, w2, w3;
    bool f0, f1, f2, f3;
    AGG_ISSUE(k0, v0, w0, f0, 0);
    AGG_ISSUE(k1, v1, w1, f1, 4);
    AGG_ISSUE(k2, v2, w2, f2, 8);
    AGG_ISSUE(k3, v3, w3, f3, 12);

    for (int jj = 0; jj < deg; jj += 16) {
        AGG_COMPUTE(k0, v0, w0, f0);
        AGG_ISSUE(k0, v0, w0, f0, jj + 16);
        AGG_COMPUTE(k1, v1, w1, f1);
        AGG_ISSUE(k1, v1, w1, f1, jj + 20);
        AGG_COMPUTE(k2, v2, w2, f2);
        AGG_ISSUE(k2, v2, w2, f2, jj + 24);
        AGG_COMPUTE(k3, v3, w3, f3);
        AGG_ISSUE(k3, v3, w3, f3, jj + 28);
    }

    // reduce over the 4 edge slots (lane bits 4,5)
    sp  += __shfl_xor(sp, 16);  sp  += __shfl_xor(sp, 32);
    spw += __shfl_xor(spw, 16); spw += __shfl_xor(spw, 32);
    #pragma unroll
    for (int i = 0; i < 8; ++i) {
        a[i] += __shfl_xor(a[i], 16);
        a[i] += __shfl_xor(a[i], 32);
    }

    // per-head normalize + rank-1 edge-attr contribution
    const float inv = 1.f / (sp + 1e-16f);
    a[0] = (a[0] + spw*weA.x + sp*beA.x) * inv;
    a[1] = (a[1] + spw*weA.y + sp*beA.y) * inv;
    a[2] = (a[2] + spw*weA.z + sp*beA.z) * inv;
    a[3] = (a[3] + spw*weA.w + sp*beA.w) * inv;
    a[4] = (a[4] + spw*weB.x + sp*beB.x) * inv;
    a[5] = (a[5] + spw*weB.y + sp*beB.y) * inv;
    a[6] = (a[6] + spw*weB.z + sp*beB.z) * inv;
    a[7] = (a[7] + spw*weB.w + sp*beB.w) * inv;

    // mean over the 4 heads (lane bits 2,3)
    #pragma unroll
    for (int i = 0; i < 8; ++i) {
        a[i] += __shfl_xor(a[i], 4);
        a[i] += __shfl_xor(a[i], 8);
    }

    if (l < 4) {   // slot 0, q = 0..3 -> dims q*8..q*8+7
        *(float4*)(G + (size_t)node * 32 + q * 8) =
            make_float4(a[0]*0.25f, a[1]*0.25f, a[2]*0.25f, a[3]*0.25f);
        *(float4*)(G + (size_t)node * 32 + q * 8 + 4) =
            make_float4(a[4]*0.25f, a[5]*0.25f, a[6]*0.25f, a[7]*0.25f);
    }
}

// ---------------------------------------------------------------------------
// node_pass (v2): Wm lives in VGPRs, not LDS. Each thread's column pair
// (c, c+128) with c = tid&127 is invariant across the node loop; the 64
// weights fit in 64 VGPRs, loaded ONCE from global (coalesced, L2-hot).
// LDS keeps only yl (8 KB). Inner loop per node: 8 broadcast ds_read_b128
// + 64 reg-reg FMAs + 2 fast_tanh.
// ---------------------------------------------------------------------------
__global__ __launch_bounds__(256, 4) void node_pass(
    const float* __restrict__ x,
    const float* __restrict__ G, const float* __restrict__ S,
    const float* __restrict__ Wmlp, const float* __restrict__ bmlp,
    float* __restrict__ out)
{
    __shared__ float yl[64 * 32];

    const int tid = threadIdx.x;
    const int c = tid & 127;            // fixed output column pair (c, c+128)
    const int half = tid >> 7;          // which node of each row pair

    float w1[32], w2[32];
    #pragma unroll
    for (int d = 0; d < 32; ++d) {
        w1[d] = Wmlp[d * 256 + c];
        w2[d] = Wmlp[d * 256 + c + 128];
    }
    const float b1 = bmlp[c];
    const float b2 = bmlp[c + 128];

    const int n0 = blockIdx.x * 64;

    // stage y = tanh(G+S): 512 float4s by 256 threads, vectorized
    for (int i4 = tid; i4 < 512; i4 += 256) {
        const int n = n0 + (i4 >> 3);
        const int d0 = (i4 & 7) * 4;
        float4 yv = make_float4(0.f, 0.f, 0.f, 0.f);
        if (n < NNODES) {
            const float4 gv = *(const float4*)(G + (size_t)n * 32 + d0);
            const float4 sv = *(const float4*)(S + (size_t)n * 32 + d0);
            yv.x = fast_tanh(gv.x + sv.x);
            yv.y = fast_tanh(gv.y + sv.y);
            yv.z = fast_tanh(gv.z + sv.z);
            yv.w = fast_tanh(gv.w + sv.w);
        }
        *(float4*)&yl[i4 * 4] = yv;
    }
    __syncthreads();

    for (int k = 0; k < 32; ++k) {
        const int nl = 2 * k + half;
        const int n = n0 + nl;
        if (n >= NNODES) continue;

        const float4* yr = (const float4*)&yl[nl * 32];  // wave-uniform -> broadcast
        float s1 = b1, s2 = b2;
        #pragma unroll
        for (int d8 = 0; d8 < 8; ++d8) {
            const float4 y4 = yr[d8];
            s1 = fmaf(y4.x, w1[d8 * 4 + 0], s1);
            s2 = fmaf(y4.x, w2[d8 * 4 + 0], s2);
            s1 = fmaf(y4.y, w1[d8 * 4 + 1], s1);
            s2 = fmaf(y4.y, w2[d8 * 4 + 1], s2);
            s1 = fmaf(y4.z, w1[d8 * 4 + 2], s1);
            s2 = fmaf(y4.z, w2[d8 * 4 + 2], s2);
            s1 = fmaf(y4.w, w1[d8 * 4 + 3], s1);
            s2 = fmaf(y4.w, w2[d8 * 4 + 3], s2);
        }
        const float z1 = fast_tanh(s1);
        const float z2 = fast_tanh(s2);
        out[(size_t)n * 128 + c] = fmaf(x[(size_t)n * 128 + c], z1, z2);
    }
}

// ---------------------------------------------------------------------------
extern "C" void kernel_launch(void* const* d_in, const int* in_sizes, int n_in,
                              void* d_out, int out_size, void* d_ws, size_t ws_size,
                              hipStream_t stream) {
    const float* x     = (const float*)d_in[0];
    const float* t     = (const float*)d_in[1];
    const int*   ei    = (const int*)  d_in[2];
    const float* ew    = (const float*)d_in[3];
    const float* Wq    = (const float*)d_in[4];
    const float* bq    = (const float*)d_in[5];
    const float* Wk    = (const float*)d_in[6];
    const float* bk    = (const float*)d_in[7];
    const float* Wv    = (const float*)d_in[8];
    const float* bv    = (const float*)d_in[9];
    const float* We    = (const float*)d_in[10];
    const float* be    = (const float*)d_in[11];
    const float* Wskip = (const float*)d_in[12];
    const float* bskip = (const float*)d_in[13];
    const float* Wmlp  = (const float*)d_in[14];
    const float* bmlp  = (const float*)d_in[15];

    char* p = (char*)d_ws;
    unsigned short* Qb  = (unsigned short*)p; p += (size_t)NNODES * 128 * 2;
    unsigned short* KVb = (unsigned short*)p; p += (size_t)NNODES * 256 * 2;
    float* S       = (float*)p; p += (size_t)NNODES * 32 * 4;
    float* G       = (float*)p; p += (size_t)NNODES * 32 * 4;
    unsigned short* Wtf = (unsigned short*)p; p += 416 * 256 * 2;
    float* biascat = (float*)p; p += 416 * 4;
    unsigned short* y0f = (unsigned short*)p; p += (size_t)NPAD * 256 * 2;
    int2* einfo    = (int2*)p;  p += (size_t)NNODES * CAP * 8;
    int* cnt       = (int*)p;   p += NNODES * 4;

    hipMemsetAsync(cnt, 0, (size_t)NNODES * sizeof(int), stream);

    prep_w<<<416, 256, 0, stream>>>(Wq, bq, Wk, bk, Wv, bv, Wskip, bskip,
                                    Wtf, biascat);

    pack_a<<<(NPAD * 32) / 256, 256, 0, stream>>>(x, t, y0f);

    // fused gemm + scatter: 1564 gemm blocks + 3125 scatter blocks,
    // interleaved 2 scatter : 1 gemm so both kinds dispatch from t=0.
    gemm_scatter<<<GEMM_BLOCKS * 3, 256, 0, stream>>>(
        y0f, Wtf, biascat, Qb, KVb, S, ei, ew, cnt, einfo);

    agg_pass<<<(NNODES + 3) / 4, 256, 0, stream>>>(cnt, einfo, We, be, Qb, KVb, G);

    node_pass<<<(NNODES + 63) / 64, 256, 0, stream>>>(x, G, S, Wmlp, bmlp,
                                                      (float*)d_out);
}